// Round 4
// baseline (527.779 us; speedup 1.0000x reference)
//
#include <hip/hip_runtime.h>
#include <hip/hip_bf16.h>
#include <math.h>
#include <string.h>

#define BN 131072   // B*N total rows

typedef __attribute__((ext_vector_type(8))) short bf16x8;
typedef __attribute__((ext_vector_type(4))) float f32x4;

__device__ __forceinline__ unsigned short f2bf(float f) {
    unsigned int u = __float_as_uint(f);
    u += 0x7fffu + ((u >> 16) & 1u);      // round-to-nearest-even
    return (unsigned short)(u >> 16);
}

// packed fp32x2 -> bf16x2 (v_cvt_pk_bf16_f32 on gfx950); low 16 bits = a
__device__ __forceinline__ unsigned int pk_bf16(float a, float b) {
    __hip_bfloat162 h = __float22bfloat162_rn(float2{a, b});
    unsigned int u;
    memcpy(&u, &h, 4);
    return u;
}

// ---------------------------------------------------------------------------
// prep: clusters_T[kg][d] = bf16(clusters[d][kg] * bn_scale[kg]);
//       bnadd[kg] = bias - mean*scale.  40960 elements, 160 blocks.
// ---------------------------------------------------------------------------
__global__ __launch_bounds__(256) void prep(
    const float* __restrict__ clusters, const float* __restrict__ bnw,
    const float* __restrict__ bnb, const float* __restrict__ rm,
    const float* __restrict__ rv,
    unsigned short* __restrict__ cT, float* __restrict__ bnadd)
{
    int i = blockIdx.x * 256 + threadIdx.x;      // 0..40959
    int d = i / 80;
    int kg = i - d * 80;
    float mul = bnw[kg] * rsqrtf(rv[kg] + 1e-5f);
    cT[kg * 512 + d] = f2bf(clusters[i] * mul);
    if (i < 80) bnadd[i] = bnb[i] - rm[i] * mul;
}

// ---------------------------------------------------------------------------
// pass_a: logits = x @ (clusters*sc)  via bf16 MFMA, +add, softmax over 80,
// write assign_T[64][BN] bf16, accumulate a_sum[b][64].
// Block 256 thr / 4 waves, 64 rows. Grid 2048.   (round-2 proven structure;
// only change: packed bf16 converts in staging and epilogue)
// ---------------------------------------------------------------------------
__global__ __launch_bounds__(256) void pass_a(
    const float* __restrict__ x, const unsigned short* __restrict__ cT,
    const float* __restrict__ bnadd,
    unsigned short* __restrict__ assignT, float* __restrict__ a_sum)
{
    __shared__ unsigned short xs[64 * 136];   // [row][d-chunk] pad->136
    __shared__ unsigned short cs[80 * 136];   // [kg][d-chunk]

    const int tid = threadIdx.x;
    const int w = tid >> 6, lane = tid & 63;
    const int q = lane >> 4, m = lane & 15;
    const int rowbase = blockIdx.x * 64;
    const int b = rowbase >> 11;              // N = 2048

    f32x4 acc[5];
#pragma unroll
    for (int t = 0; t < 5; ++t) acc[t] = (f32x4){0.f, 0.f, 0.f, 0.f};

    for (int c = 0; c < 4; ++c) {
        // stage x chunk [64 rows][128 d], fp32 -> bf16 (packed cvt)
#pragma unroll
        for (int r = 0; r < 8; ++r) {
            int i = tid + 256 * r;            // 2048 float4
            int row = i >> 5, dd = (i & 31) * 4;
            float4 v = *(const float4*)(x + (size_t)(rowbase + row) * 512 + c * 128 + dd);
            uint2 p = { pk_bf16(v.x, v.y), pk_bf16(v.z, v.w) };
            *(uint2*)&xs[row * 136 + dd] = p;
        }
        // stage clusters_T chunk [80][128] bf16
#pragma unroll
        for (int r = 0; r < 10; ++r) {
            int i = tid + 256 * r;            // 2560 ushort4
            int kg = i >> 5, dd = (i & 31) * 4;
            *(ushort4*)&cs[kg * 136 + dd] = *(const ushort4*)(cT + kg * 512 + c * 128 + dd);
        }
        __syncthreads();
#pragma unroll
        for (int ks = 0; ks < 4; ++ks) {
            bf16x8 a = *(const bf16x8*)&xs[(w * 16 + m) * 136 + ks * 32 + q * 8];
#pragma unroll
            for (int t = 0; t < 5; ++t) {
                bf16x8 bb = *(const bf16x8*)&cs[(m + 16 * t) * 136 + ks * 32 + q * 8];
                acc[t] = __builtin_amdgcn_mfma_f32_16x16x32_bf16(a, bb, acc[t], 0, 0, 0);
            }
        }
        __syncthreads();
    }

    float addv[5];
#pragma unroll
    for (int t = 0; t < 5; ++t) addv[t] = bnadd[m + 16 * t];

    // softmax over 80: row i lives in 16 lanes (same quad) x 5 tiles
    float e[5][4], rs4[4];
#pragma unroll
    for (int i = 0; i < 4; ++i) {
        float v[5];
#pragma unroll
        for (int t = 0; t < 5; ++t) v[t] = acc[t][i] + addv[t];
        float mx = v[0];
#pragma unroll
        for (int t = 1; t < 5; ++t) mx = fmaxf(mx, v[t]);
        mx = fmaxf(mx, __shfl_xor(mx, 1, 64));
        mx = fmaxf(mx, __shfl_xor(mx, 2, 64));
        mx = fmaxf(mx, __shfl_xor(mx, 4, 64));
        mx = fmaxf(mx, __shfl_xor(mx, 8, 64));
        float sum = 0.f;
#pragma unroll
        for (int t = 0; t < 5; ++t) { e[t][i] = __expf(v[t] - mx); sum += e[t][i]; }
        sum += __shfl_xor(sum, 1, 64);
        sum += __shfl_xor(sum, 2, 64);
        sum += __shfl_xor(sum, 4, 64);
        sum += __shfl_xor(sum, 8, 64);
        rs4[i] = 1.0f / sum;
    }

    const int n0 = rowbase + w * 16 + q * 4;
#pragma unroll
    for (int t = 0; t < 4; ++t) {
        float a0 = e[t][0] * rs4[0], a1 = e[t][1] * rs4[1];
        float a2 = e[t][2] * rs4[2], a3 = e[t][3] * rs4[3];
        uint2 h = { pk_bf16(a0, a1), pk_bf16(a2, a3) };
        *(uint2*)(assignT + (size_t)(m + 16 * t) * BN + n0) = h;
        float as = a0 + a1 + a2 + a3;
        as += __shfl_xor(as, 16, 64);
        as += __shfl_xor(as, 32, 64);
        if (lane < 16) atomicAdd(&a_sum[b * 64 + m + 16 * t], as);
    }
}

// ---------------------------------------------------------------------------
// pass_b: vlad[b][d][kc] = sum_n x[b,n,d]*assign[b,n,kc] - a_sum*clusters2.
// A = x^T (transposed LDS u16 reads), B = assign_T (clean b128 reads).
// Block 256 thr / 4 waves: tile 64 d x 64 kc; grid (8 d-tiles, 64 b).
// (round-2 proven structure; only change: packed bf16 converts in staging)
// ---------------------------------------------------------------------------
__global__ __launch_bounds__(256) void pass_b(
    const float* __restrict__ x, const unsigned short* __restrict__ assignT,
    const float* __restrict__ a_sum, const float* __restrict__ clusters2,
    float* __restrict__ vlad, float* __restrict__ colssq)
{
    __shared__ unsigned short xs2[64 * 130];  // [n][d] pad->130 (quad bank spread)
    __shared__ unsigned short as2[64 * 72];   // [kc][n] pad->72 (b128 aligned)

    const int tid = threadIdx.x;
    const int w = tid >> 6, lane = tid & 63;
    const int q = lane >> 4, m = lane & 15;
    const int dt = blockIdx.x;                // 0..7
    const int b = blockIdx.y;

    f32x4 acc[4];
#pragma unroll
    for (int t = 0; t < 4; ++t) acc[t] = (f32x4){0.f, 0.f, 0.f, 0.f};

    for (int nc = 0; nc < 2048; nc += 64) {
        // stage x chunk [64 n][64 d] fp32 -> bf16 LDS (packed cvt)
#pragma unroll
        for (int r = 0; r < 4; ++r) {
            int i = tid + 256 * r;            // 1024 float4
            int nl = i >> 4, dd = (i & 15) * 4;
            float4 v = *(const float4*)(x + (size_t)(b * 2048 + nc + nl) * 512 + dt * 64 + dd);
            *(unsigned int*)&xs2[nl * 130 + dd]     = pk_bf16(v.x, v.y);
            *(unsigned int*)&xs2[nl * 130 + dd + 2] = pk_bf16(v.z, v.w);
        }
        // stage assign_T chunk [64 kc][64 n]
#pragma unroll
        for (int r = 0; r < 4; ++r) {
            int i = tid + 256 * r;            // 1024 ushort4
            int kc = i >> 4, nl4 = (i & 15) * 4;
            *(ushort4*)&as2[kc * 72 + nl4] =
                *(const ushort4*)(assignT + (size_t)kc * BN + b * 2048 + nc + nl4);
        }
        __syncthreads();
#pragma unroll
        for (int ks = 0; ks < 2; ++ks) {
            union { unsigned short u[8]; bf16x8 v; } af;
            const int dcol = w * 16 + m;
#pragma unroll
            for (int j = 0; j < 8; ++j)
                af.u[j] = xs2[(ks * 32 + q * 8 + j) * 130 + dcol];
#pragma unroll
            for (int nt = 0; nt < 4; ++nt) {
                bf16x8 bb = *(const bf16x8*)&as2[(nt * 16 + m) * 72 + ks * 32 + q * 8];
                acc[nt] = __builtin_amdgcn_mfma_f32_16x16x32_bf16(af.v, bb, acc[nt], 0, 0, 0);
            }
        }
        __syncthreads();
    }

    const int d0 = dt * 64 + w * 16 + q * 4;
#pragma unroll
    for (int nt = 0; nt < 4; ++nt) {
        int kc = nt * 16 + m;
        float asv = a_sum[b * 64 + kc];
        float ss = 0.f;
#pragma unroll
        for (int i = 0; i < 4; ++i) {
            int d = d0 + i;
            float v = acc[nt][i] - asv * clusters2[d * 64 + kc];
            vlad[((size_t)b * 512 + d) * 64 + kc] = v;
            ss += v * v;
        }
        ss += __shfl_xor(ss, 16, 64);
        ss += __shfl_xor(ss, 32, 64);
        if (lane < 16) atomicAdd(&colssq[b * 64 + kc], ss);
    }
}

// ---------------------------------------------------------------------------
// pass_c: per-column scale from colssq, global scale, write out.
// Grid (8 segs, 64 b).
// ---------------------------------------------------------------------------
__global__ __launch_bounds__(256) void pass_c(
    const float* __restrict__ vlad, const float* __restrict__ colssq,
    float* __restrict__ out)
{
    __shared__ float sc[65];
    const int b = blockIdx.y, seg = blockIdx.x, tid = threadIdx.x;

    if (tid < 64) {
        float css = colssq[b * 64 + tid];
        float invc = 1.0f / fmaxf(sqrtf(css), 1e-12f);
        sc[tid] = invc;
        float ns = css * invc * invc;     // squared norm of normalized column
        ns += __shfl_xor(ns, 1, 64);
        ns += __shfl_xor(ns, 2, 64);
        ns += __shfl_xor(ns, 4, 64);
        ns += __shfl_xor(ns, 8, 64);
        ns += __shfl_xor(ns, 16, 64);
        ns += __shfl_xor(ns, 32, 64);
        if (tid == 0) sc[64] = 1.0f / fmaxf(sqrtf(ns), 1e-12f);
    }
    __syncthreads();
    const float invr = sc[64];

#pragma unroll
    for (int r = 0; r < 4; ++r) {
        int i4 = seg * 1024 + r * 256 + tid;
        float4 v = *(const float4*)(vlad + (size_t)b * 32768 + (size_t)i4 * 4);
        int c0 = (i4 & 15) * 4;
        float4 o;
        o.x = v.x * sc[c0 + 0] * invr;
        o.y = v.y * sc[c0 + 1] * invr;
        o.z = v.z * sc[c0 + 2] * invr;
        o.w = v.w * sc[c0 + 3] * invr;
        *(float4*)(out + (size_t)b * 32768 + (size_t)i4 * 4) = o;
    }
}

extern "C" void kernel_launch(void* const* d_in, const int* in_sizes, int n_in,
                              void* d_out, int out_size, void* d_ws, size_t ws_size,
                              hipStream_t stream)
{
    const float* x         = (const float*)d_in[0];
    const float* clusters  = (const float*)d_in[1];
    const float* clusters2 = (const float*)d_in[2];
    const float* bn_w      = (const float*)d_in[3];
    const float* bn_b      = (const float*)d_in[4];
    const float* rmean     = (const float*)d_in[5];
    const float* rvar      = (const float*)d_in[6];
    float* out = (float*)d_out;

    char* ws = (char*)d_ws;
    float* a_sum            = (float*)(ws + 0);            // 16 KB
    float* colssq           = (float*)(ws + 16384);        // 16 KB
    float* bnadd            = (float*)(ws + 32768);        // 320 B
    unsigned short* cT      = (unsigned short*)(ws + 65536);       // 80 KB
    unsigned short* assignT = (unsigned short*)(ws + 262144);      // 16 MB
    float* vlad             = (float*)(ws + 262144 + 16777216);    // 8 MB

    hipMemsetAsync(ws, 0, 32768, stream);   // a_sum + colssq

    prep<<<160, 256, 0, stream>>>(clusters, bn_w, bn_b, rmean, rvar, cT, bnadd);
    pass_a<<<2048, 256, 0, stream>>>(x, cT, bnadd, assignT, a_sum);
    pass_b<<<dim3(8, 64), 256, 0, stream>>>(x, assignT, a_sum, clusters2, vlad, colssq);
    pass_c<<<dim3(8, 64), 256, 0, stream>>>(vlad, colssq, out);
}

// Round 5
// 449.783 us; speedup vs baseline: 1.1734x; 1.1734x over previous
//
#include <hip/hip_runtime.h>
#include <hip/hip_bf16.h>
#include <math.h>
#include <string.h>

#define BN 131072   // B*N total rows

typedef __attribute__((ext_vector_type(8))) short bf16x8;
typedef __attribute__((ext_vector_type(4))) float f32x4;

__device__ __forceinline__ unsigned short f2bf(float f) {
    unsigned int u = __float_as_uint(f);
    u += 0x7fffu + ((u >> 16) & 1u);      // round-to-nearest-even
    return (unsigned short)(u >> 16);
}

// packed fp32x2 -> bf16x2 (v_cvt_pk_bf16_f32 on gfx950); low 16 bits = a
__device__ __forceinline__ unsigned int pk_bf16(float a, float b) {
    __hip_bfloat162 h = __float22bfloat162_rn(float2{a, b});
    unsigned int u;
    memcpy(&u, &h, 4);
    return u;
}

// ---------------------------------------------------------------------------
// prep: clusters_T[kg][d] = bf16(clusters[d][kg] * bn_scale[kg]);
//       bnadd[kg] = bias - mean*scale.  40960 elements, 160 blocks.
// ---------------------------------------------------------------------------
__global__ __launch_bounds__(256) void prep(
    const float* __restrict__ clusters, const float* __restrict__ bnw,
    const float* __restrict__ bnb, const float* __restrict__ rm,
    const float* __restrict__ rv,
    unsigned short* __restrict__ cT, float* __restrict__ bnadd)
{
    int i = blockIdx.x * 256 + threadIdx.x;      // 0..40959
    int d = i / 80;
    int kg = i - d * 80;
    float mul = bnw[kg] * rsqrtf(rv[kg] + 1e-5f);
    cT[kg * 512 + d] = f2bf(clusters[i] * mul);
    if (i < 80) bnadd[i] = bnb[i] - rm[i] * mul;
}

// ---------------------------------------------------------------------------
// pass_a: logits = x @ (clusters*sc) via bf16 MFMA, +add, softmax over 80,
// write assign_T[64][BN] bf16, accumulate a_sum[b][64].
// Block 256 thr / 4 waves, 64 rows. Grid 2048.
// Round-4 proven structure + register prefetch pipeline (chunk c+1 global
// loads issued after barrier1 of chunk c, overlapping the MFMA loop).
// ---------------------------------------------------------------------------
__global__ __launch_bounds__(256) void pass_a(
    const float* __restrict__ x, const unsigned short* __restrict__ cT,
    const float* __restrict__ bnadd,
    unsigned short* __restrict__ assignT, float* __restrict__ a_sum)
{
    __shared__ unsigned short xs[64 * 136];   // [row][d-chunk] pad->136
    __shared__ unsigned short cs[80 * 136];   // [kg][d-chunk]

    const int tid = threadIdx.x;
    const int w = tid >> 6, lane = tid & 63;
    const int q = lane >> 4, m = lane & 15;
    const int rowbase = blockIdx.x * 64;
    const int b = rowbase >> 11;              // N = 2048

    f32x4 acc[5];
#pragma unroll
    for (int t = 0; t < 5; ++t) acc[t] = (f32x4){0.f, 0.f, 0.f, 0.f};

    float4  vx[8];
    ushort4 vc[10];

    // prologue: preload chunk 0 into registers
#pragma unroll
    for (int r = 0; r < 8; ++r) {
        int i = tid + 256 * r;
        int row = i >> 5, dd = (i & 31) * 4;
        vx[r] = *(const float4*)(x + (size_t)(rowbase + row) * 512 + dd);
    }
#pragma unroll
    for (int r = 0; r < 10; ++r) {
        int i = tid + 256 * r;
        int kg = i >> 5, dd = (i & 31) * 4;
        vc[r] = *(const ushort4*)(cT + kg * 512 + dd);
    }

    for (int c = 0; c < 4; ++c) {
        // write staged registers to LDS (cvt here)
#pragma unroll
        for (int r = 0; r < 8; ++r) {
            int i = tid + 256 * r;
            int row = i >> 5, dd = (i & 31) * 4;
            uint2 p = { pk_bf16(vx[r].x, vx[r].y), pk_bf16(vx[r].z, vx[r].w) };
            *(uint2*)&xs[row * 136 + dd] = p;
        }
#pragma unroll
        for (int r = 0; r < 10; ++r) {
            int i = tid + 256 * r;
            int kg = i >> 5, dd = (i & 31) * 4;
            *(ushort4*)&cs[kg * 136 + dd] = vc[r];
        }
        __syncthreads();

        // prefetch next chunk's global data (overlaps MFMA below)
        if (c < 3) {
#pragma unroll
            for (int r = 0; r < 8; ++r) {
                int i = tid + 256 * r;
                int row = i >> 5, dd = (i & 31) * 4;
                vx[r] = *(const float4*)(x + (size_t)(rowbase + row) * 512 + (c + 1) * 128 + dd);
            }
#pragma unroll
            for (int r = 0; r < 10; ++r) {
                int i = tid + 256 * r;
                int kg = i >> 5, dd = (i & 31) * 4;
                vc[r] = *(const ushort4*)(cT + kg * 512 + (c + 1) * 128 + dd);
            }
        }

#pragma unroll
        for (int ks = 0; ks < 4; ++ks) {
            bf16x8 a = *(const bf16x8*)&xs[(w * 16 + m) * 136 + ks * 32 + q * 8];
#pragma unroll
            for (int t = 0; t < 5; ++t) {
                bf16x8 bb = *(const bf16x8*)&cs[(m + 16 * t) * 136 + ks * 32 + q * 8];
                acc[t] = __builtin_amdgcn_mfma_f32_16x16x32_bf16(a, bb, acc[t], 0, 0, 0);
            }
        }
        __syncthreads();
    }

    float addv[5];
#pragma unroll
    for (int t = 0; t < 5; ++t) addv[t] = bnadd[m + 16 * t];

    // softmax over 80: row i lives in 16 lanes (same quad) x 5 tiles
    float e[5][4], rs4[4];
#pragma unroll
    for (int i = 0; i < 4; ++i) {
        float v[5];
#pragma unroll
        for (int t = 0; t < 5; ++t) v[t] = acc[t][i] + addv[t];
        float mx = v[0];
#pragma unroll
        for (int t = 1; t < 5; ++t) mx = fmaxf(mx, v[t]);
        mx = fmaxf(mx, __shfl_xor(mx, 1, 64));
        mx = fmaxf(mx, __shfl_xor(mx, 2, 64));
        mx = fmaxf(mx, __shfl_xor(mx, 4, 64));
        mx = fmaxf(mx, __shfl_xor(mx, 8, 64));
        float sum = 0.f;
#pragma unroll
        for (int t = 0; t < 5; ++t) { e[t][i] = __expf(v[t] - mx); sum += e[t][i]; }
        sum += __shfl_xor(sum, 1, 64);
        sum += __shfl_xor(sum, 2, 64);
        sum += __shfl_xor(sum, 4, 64);
        sum += __shfl_xor(sum, 8, 64);
        rs4[i] = 1.0f / sum;
    }

    const int n0 = rowbase + w * 16 + q * 4;
#pragma unroll
    for (int t = 0; t < 4; ++t) {
        float a0 = e[t][0] * rs4[0], a1 = e[t][1] * rs4[1];
        float a2 = e[t][2] * rs4[2], a3 = e[t][3] * rs4[3];
        uint2 h = { pk_bf16(a0, a1), pk_bf16(a2, a3) };
        *(uint2*)(assignT + (size_t)(m + 16 * t) * BN + n0) = h;
        float as = a0 + a1 + a2 + a3;
        as += __shfl_xor(as, 16, 64);
        as += __shfl_xor(as, 32, 64);
        if (lane < 16) atomicAdd(&a_sum[b * 64 + m + 16 * t], as);
    }
}

// ---------------------------------------------------------------------------
// pass_b: partial vlad over an n-half. Grid (8 dt, 64 b, 2 ns) = 1024 blocks.
// Each block: tile 64 d x 64 kc over 1024 n; writes its own partial buffer
// (no atomics). ns==0 also subtracts a_sum*clusters2. Register prefetch.
// ---------------------------------------------------------------------------
__global__ __launch_bounds__(256) void pass_b(
    const float* __restrict__ x, const unsigned short* __restrict__ assignT,
    const float* __restrict__ a_sum, const float* __restrict__ clusters2,
    float* __restrict__ part)     // [2][64][512][64]
{
    __shared__ unsigned short xs2[64 * 130];  // [n][d] pad->130
    __shared__ unsigned short as2[64 * 72];   // [kc][n] pad->72

    const int tid = threadIdx.x;
    const int w = tid >> 6, lane = tid & 63;
    const int q = lane >> 4, m = lane & 15;
    const int dt = blockIdx.x;                // 0..7
    const int b = blockIdx.y;
    const int ns = blockIdx.z;                // 0..1
    const int nbase = ns * 1024;

    f32x4 acc[4];
#pragma unroll
    for (int t = 0; t < 4; ++t) acc[t] = (f32x4){0.f, 0.f, 0.f, 0.f};

    float4  vx[4];
    ushort4 va[4];

    // prologue: preload first chunk
#pragma unroll
    for (int r = 0; r < 4; ++r) {
        int i = tid + 256 * r;
        int nl = i >> 4, dd = (i & 15) * 4;
        vx[r] = *(const float4*)(x + (size_t)(b * 2048 + nbase + nl) * 512 + dt * 64 + dd);
    }
#pragma unroll
    for (int r = 0; r < 4; ++r) {
        int i = tid + 256 * r;
        int kc = i >> 4, nl4 = (i & 15) * 4;
        va[r] = *(const ushort4*)(assignT + (size_t)kc * BN + b * 2048 + nbase + nl4);
    }

    for (int nc = nbase; nc < nbase + 1024; nc += 64) {
        // write staged registers to LDS
#pragma unroll
        for (int r = 0; r < 4; ++r) {
            int i = tid + 256 * r;
            int nl = i >> 4, dd = (i & 15) * 4;
            *(unsigned int*)&xs2[nl * 130 + dd]     = pk_bf16(vx[r].x, vx[r].y);
            *(unsigned int*)&xs2[nl * 130 + dd + 2] = pk_bf16(vx[r].z, vx[r].w);
        }
#pragma unroll
        for (int r = 0; r < 4; ++r) {
            int i = tid + 256 * r;
            int kc = i >> 4, nl4 = (i & 15) * 4;
            *(ushort4*)&as2[kc * 72 + nl4] = va[r];
        }
        __syncthreads();

        // prefetch next chunk (overlaps MFMA below)
        if (nc + 64 < nbase + 1024) {
#pragma unroll
            for (int r = 0; r < 4; ++r) {
                int i = tid + 256 * r;
                int nl = i >> 4, dd = (i & 15) * 4;
                vx[r] = *(const float4*)(x + (size_t)(b * 2048 + nc + 64 + nl) * 512 + dt * 64 + dd);
            }
#pragma unroll
            for (int r = 0; r < 4; ++r) {
                int i = tid + 256 * r;
                int kc = i >> 4, nl4 = (i & 15) * 4;
                va[r] = *(const ushort4*)(assignT + (size_t)kc * BN + b * 2048 + nc + 64 + nl4);
            }
        }

#pragma unroll
        for (int ks = 0; ks < 2; ++ks) {
            union { unsigned short u[8]; bf16x8 v; } af;
            const int dcol = w * 16 + m;
#pragma unroll
            for (int j = 0; j < 8; ++j)
                af.u[j] = xs2[(ks * 32 + q * 8 + j) * 130 + dcol];
#pragma unroll
            for (int nt = 0; nt < 4; ++nt) {
                bf16x8 bb = *(const bf16x8*)&as2[(nt * 16 + m) * 72 + ks * 32 + q * 8];
                acc[nt] = __builtin_amdgcn_mfma_f32_16x16x32_bf16(af.v, bb, acc[nt], 0, 0, 0);
            }
        }
        __syncthreads();
    }

    float* dst = part + (size_t)ns * (64 * 512 * 64);
    const int d0 = dt * 64 + w * 16 + q * 4;
#pragma unroll
    for (int nt = 0; nt < 4; ++nt) {
        int kc = nt * 16 + m;
        float asv = (ns == 0) ? a_sum[b * 64 + kc] : 0.f;
#pragma unroll
        for (int i = 0; i < 4; ++i) {
            int d = d0 + i;
            float v = acc[nt][i] - asv * clusters2[d * 64 + kc];
            dst[((size_t)b * 512 + d) * 64 + kc] = v;
        }
    }
}

// ---------------------------------------------------------------------------
// pass_c1: vlad = part0 + part1; accumulate colssq[b][k]. Grid (8 seg, 64 b).
// ---------------------------------------------------------------------------
__global__ __launch_bounds__(256) void pass_c1(
    const float* __restrict__ part, float* __restrict__ vlad,
    float* __restrict__ colssq)
{
    __shared__ float red[256];
    const int b = blockIdx.y, seg = blockIdx.x, tid = threadIdx.x;
    const int k = tid & 63, dg = tid >> 6;    // 4 d-groups of 16
    const float* p0 = part;
    const float* p1 = part + (size_t)(64 * 512 * 64);

    float ssq = 0.f;
#pragma unroll
    for (int j = 0; j < 16; ++j) {
        int d = seg * 64 + dg + j * 4;
        size_t idx = ((size_t)b * 512 + d) * 64 + k;
        float v = p0[idx] + p1[idx];
        vlad[idx] = v;
        ssq += v * v;
    }
    red[tid] = ssq;
    __syncthreads();
    if (tid < 64)
        atomicAdd(&colssq[b * 64 + k], red[k] + red[64 + k] + red[128 + k] + red[192 + k]);
}

// ---------------------------------------------------------------------------
// pass_c2: per-column scale from colssq, global scale, write out.
// Grid (8 segs, 64 b).
// ---------------------------------------------------------------------------
__global__ __launch_bounds__(256) void pass_c2(
    const float* __restrict__ vlad, const float* __restrict__ colssq,
    float* __restrict__ out)
{
    __shared__ float sc[65];
    const int b = blockIdx.y, seg = blockIdx.x, tid = threadIdx.x;

    if (tid < 64) {
        float css = colssq[b * 64 + tid];
        float invc = 1.0f / fmaxf(sqrtf(css), 1e-12f);
        sc[tid] = invc;
        float ns = css * invc * invc;     // squared norm of normalized column
        ns += __shfl_xor(ns, 1, 64);
        ns += __shfl_xor(ns, 2, 64);
        ns += __shfl_xor(ns, 4, 64);
        ns += __shfl_xor(ns, 8, 64);
        ns += __shfl_xor(ns, 16, 64);
        ns += __shfl_xor(ns, 32, 64);
        if (tid == 0) sc[64] = 1.0f / fmaxf(sqrtf(ns), 1e-12f);
    }
    __syncthreads();
    const float invr = sc[64];

#pragma unroll
    for (int r = 0; r < 4; ++r) {
        int i4 = seg * 1024 + r * 256 + tid;
        float4 v = *(const float4*)(vlad + (size_t)b * 32768 + (size_t)i4 * 4);
        int c0 = (i4 & 15) * 4;
        float4 o;
        o.x = v.x * sc[c0 + 0] * invr;
        o.y = v.y * sc[c0 + 1] * invr;
        o.z = v.z * sc[c0 + 2] * invr;
        o.w = v.w * sc[c0 + 3] * invr;
        *(float4*)(out + (size_t)b * 32768 + (size_t)i4 * 4) = o;
    }
}

extern "C" void kernel_launch(void* const* d_in, const int* in_sizes, int n_in,
                              void* d_out, int out_size, void* d_ws, size_t ws_size,
                              hipStream_t stream)
{
    const float* x         = (const float*)d_in[0];
    const float* clusters  = (const float*)d_in[1];
    const float* clusters2 = (const float*)d_in[2];
    const float* bn_w      = (const float*)d_in[3];
    const float* bn_b      = (const float*)d_in[4];
    const float* rmean     = (const float*)d_in[5];
    const float* rvar      = (const float*)d_in[6];
    float* out = (float*)d_out;

    char* ws = (char*)d_ws;
    float* a_sum            = (float*)(ws + 0);            // 16 KB
    float* colssq           = (float*)(ws + 16384);        // 16 KB
    float* bnadd            = (float*)(ws + 32768);        // 320 B
    unsigned short* cT      = (unsigned short*)(ws + 65536);          // 80 KB
    unsigned short* assignT = (unsigned short*)(ws + 262144);         // 16 MB
    float* vlad             = (float*)(ws + 262144 + 16777216);       // 8 MB
    float* part             = (float*)(ws + 262144 + 16777216 + 8388608); // 16 MB

    hipMemsetAsync(ws, 0, 32768, stream);   // a_sum + colssq

    prep<<<160, 256, 0, stream>>>(clusters, bn_w, bn_b, rmean, rvar, cT, bnadd);
    pass_a<<<2048, 256, 0, stream>>>(x, cT, bnadd, assignT, a_sum);
    pass_b<<<dim3(8, 64, 2), 256, 0, stream>>>(x, assignT, a_sum, clusters2, part);
    pass_c1<<<dim3(8, 64), 256, 0, stream>>>(part, vlad, colssq);
    pass_c2<<<dim3(8, 64), 256, 0, stream>>>(vlad, colssq, out);
}